// Round 16
// baseline (125.532 us; speedup 1.0000x reference)
//
#include <hip/hip_runtime.h>
#include <math.h>

#define SEQ   2048
#define BATCH 2
#define NH    16
#define DKD   64
#define DM    1024
#define MTOT  (BATCH*SEQ)   // 4096

typedef short bf16x8 __attribute__((ext_vector_type(8)));      // 8 bf16 (4 VGPR)
typedef float f32x4  __attribute__((ext_vector_type(4)));      // MFMA C/D
typedef unsigned short u16x4 __attribute__((ext_vector_type(4)));

#define MFMA_B16(a,b,c) __builtin_amdgcn_mfma_f32_16x16x32_bf16((a),(b),(c),0,0,0)

__device__ __forceinline__ unsigned short f2bf(float f) {
    union { float f; unsigned int u; } v; v.f = f;
    unsigned int r = v.u + 0x7FFFu + ((v.u >> 16) & 1u);   // RNE
    return (unsigned short)(r >> 16);
}
__device__ __forceinline__ float bf2f(unsigned short h) {
    union { unsigned int u; float f; } v; v.u = ((unsigned int)h) << 16;
    return v.f;
}
__device__ __forceinline__ void gload16(const void* g, void* l) {
    __builtin_amdgcn_global_load_lds(
        (const __attribute__((address_space(1))) unsigned int*)g,
        (__attribute__((address_space(3))) unsigned int*)l, 16, 0, 0);
}

// ---------------- fp32 -> bf16: x + Wq + Wk + Wv + Wo in ONE launch ----------------
__global__ __launch_bounds__(256)
void convert_all(const float* __restrict__ x,  const float* __restrict__ Wq,
                 const float* __restrict__ Wk, const float* __restrict__ Wv,
                 const float* __restrict__ Wo,
                 unsigned short* __restrict__ Xb, unsigned short* __restrict__ Wqkvb,
                 unsigned short* __restrict__ Wob)
{
    int i = blockIdx.x * 256 + threadIdx.x;          // 0 .. 2M-1
    const float* src;
    unsigned short* dst;
    size_t off;
    if (i < (1 << 20)) {
        src = x; dst = Xb; off = (size_t)i;
    } else {
        int j = i - (1 << 20);
        int wsel = j >> 18;                          // 0..3
        off = (size_t)(j & ((1 << 18) - 1));
        src = (wsel == 0) ? Wq : (wsel == 1) ? Wk : (wsel == 2) ? Wv : Wo;
        dst = (wsel < 3) ? Wqkvb + (size_t)wsel * (1u << 20) : Wob;
    }
    float4 v = ((const float4*)src)[off];
    u16x4 o = { f2bf(v.x), f2bf(v.y), f2bf(v.z), f2bf(v.w) };
    *(u16x4*)&dst[off * 4] = o;
}

// ---------------- RoPE in place on bf16 Q/K  [bh][s][64] (standalone) ----------------
__global__ __launch_bounds__(256)
void rope_bf16(unsigned short* __restrict__ Qb, unsigned short* __restrict__ Kb,
               const int* __restrict__ pos)
{
    int g = blockIdx.x * 256 + threadIdx.x;      // 2M ushort4-groups (Q then K)
    int tsel = g >> 20;
    int i = g & ((1 << 20) - 1);
    unsigned short* base = tsel ? Kb : Qb;
    int d4 = i & 15;
    int s  = (i >> 4) & (SEQ - 1);
    float P = (float)pos[s];
    const float NEG_L2 = -0.41524101186092103f;  // -log2(10000)/32
    int p0 = d4 * 2, p1 = p0 + 1;
    float a0 = P * exp2f((float)p0 * NEG_L2);
    float a1 = P * exp2f((float)p1 * NEG_L2);
    float s0, c0, s1, c1;
    sincosf(a0, &s0, &c0);
    sincosf(a1, &s1, &c1);

    u16x4 v = *(u16x4*)&base[(size_t)i * 4];
    float x0 = bf2f(v[0]), x1 = bf2f(v[1]), x2 = bf2f(v[2]), x3 = bf2f(v[3]);
    u16x4 o = { f2bf(x0 * c0 - x1 * s0), f2bf(x0 * s0 + x1 * c0),
                f2bf(x2 * c1 - x3 * s1), f2bf(x2 * s1 + x3 * c1) };
    *(u16x4*)&base[(size_t)i * 4] = o;
}

// ---------------- MFMA GEMM (unchanged) ----------------
template<int MODE>
__global__ __launch_bounds__(256)
void gemm_mfma(const unsigned short* __restrict__ A, const unsigned short* __restrict__ B,
               unsigned short* __restrict__ Qb, unsigned short* __restrict__ Kb,
               unsigned short* __restrict__ VTb, float* __restrict__ Cf)
{
    const int t = threadIdx.x;
    const int w = t >> 6, l = t & 63, lid = l & 15, hi = (l >> 4) * 16;
    const int wm = w >> 1, wn = w & 1;
    const int m0 = blockIdx.y * 128, n0 = blockIdx.x * 128;

    __shared__ __align__(16) char At[2][8192];
    __shared__ __align__(16) char Bt[2][8192];

    f32x4 acc[4][4];
    const f32x4 z4 = {0.f, 0.f, 0.f, 0.f};
    #pragma unroll
    for (int i = 0; i < 4; ++i)
        #pragma unroll
        for (int j = 0; j < 4; ++j) acc[i][j] = z4;

    const char* Ab = (const char*)A;
    const char* Bb = (const char*)B;

    auto stage = [&](int buf, int kt) {
        const int kbyte = kt * 64;
        #pragma unroll
        for (int i = 0; i < 2; ++i) {
            int o   = i * 4096 + t * 16;
            int row = o >> 6, cb = o & 63;
            char* lbase_a = At[buf] + i * 4096 + (t >> 6) * 1024;
            char* lbase_b = Bt[buf] + i * 4096 + (t >> 6) * 1024;
            gload16(Ab + (size_t)(m0 + row) * 2048 + kbyte + cb, lbase_a);
            gload16(Bb + (size_t)(n0 + row) * 2048 + kbyte + cb, lbase_b);
        }
    };

    stage(0, 0);
    __syncthreads();

    const int NKT = DM / 32;
    for (int kt = 0; kt < NKT; ++kt) {
        const int cur = kt & 1;
        if (kt + 1 < NKT) stage(cur ^ 1, kt + 1);

        bf16x8 af[4], bfr[4];
        #pragma unroll
        for (int mf = 0; mf < 4; ++mf)
            af[mf] = *(const bf16x8*)(At[cur] + (wm * 64 + mf * 16 + lid) * 64 + hi);
        #pragma unroll
        for (int nf = 0; nf < 4; ++nf)
            bfr[nf] = *(const bf16x8*)(Bt[cur] + (wn * 64 + nf * 16 + lid) * 64 + hi);
        __builtin_amdgcn_s_setprio(1);
        #pragma unroll
        for (int mf = 0; mf < 4; ++mf)
            #pragma unroll
            for (int nf = 0; nf < 4; ++nf)
                acc[mf][nf] = MFMA_B16(af[mf], bfr[nf], acc[mf][nf]);
        __builtin_amdgcn_s_setprio(0);

        __syncthreads();
    }

    if (MODE == 1) {
        #pragma unroll
        for (int mf = 0; mf < 4; ++mf)
            #pragma unroll
            for (int nf = 0; nf < 4; ++nf) {
                int ncol = n0 + wn * 64 + nf * 16 + lid;
                #pragma unroll
                for (int jj = 0; jj < 4; ++jj) {
                    int mrow = m0 + wm * 64 + mf * 16 + (l >> 4) * 4 + jj;
                    Cf[(size_t)mrow * DM + ncol] = acc[mf][nf][jj];
                }
            }
    } else {
        const int z = n0 >> 10;                  // 0:Q 1:K 2:V
        const int nbase = n0 & 1023;
        #pragma unroll
        for (int mf = 0; mf < 4; ++mf)
            #pragma unroll
            for (int nf = 0; nf < 4; ++nf) {
                int ncol = nbase + wn * 64 + nf * 16 + lid;
                int h = ncol >> 6, d = ncol & 63;
                int mbase = m0 + wm * 64 + mf * 16 + (l >> 4) * 4;
                int b = mbase >> 11, s0v = mbase & 2047;
                if (z == 2) {
                    u16x4 pk = { f2bf(acc[mf][nf][0]), f2bf(acc[mf][nf][1]),
                                 f2bf(acc[mf][nf][2]), f2bf(acc[mf][nf][3]) };
                    *(u16x4*)&VTb[((size_t)(b * NH + h) * DKD + d) * SEQ + s0v] = pk;
                } else {
                    unsigned short* dst = (z == 0) ? Qb : Kb;
                    #pragma unroll
                    for (int jj = 0; jj < 4; ++jj)
                        dst[((size_t)(b * NH + h) * SEQ + (s0v + jj)) * DKD + d] =
                            f2bf(acc[mf][nf][jj]);
                }
            }
    }
}

// ---------------- MFMA flash attention: 8-wave blocks, ADJACENT q-tile pairs ----------
// 512 thr: waves 0-3 = q-tile A, waves 4-7 = q-tile B = A+1 (same bh); K/V staged once.
// A-half idles only its final barrier round (<=6% waste) instead of R15's far-pair 33%.
// Decode: L=by*16+bx; g=L>>8, c=L&255, j=c&15; bh=(g<<4)|(c>>4);
//   g=0: (qbA,qbB)=(2j, 2j+1) dur=2j+2;  g=1: (30-2j, 31-2j) dur=32-2j.
// Same-CU pair (L, L+256): durations sum to 34 = const -> uniform CU makespan.
// Fixed-shift softmax: P = exp2(fma(s, log2e/8, -12*log2e)); denom via ones-MFMA.
__global__ __launch_bounds__(512)
void flash_mfma(const unsigned short* __restrict__ Qb, const unsigned short* __restrict__ Kb,
                const unsigned short* __restrict__ VTb, unsigned short* __restrict__ AOb)
{
    const int L  = blockIdx.y * 16 + blockIdx.x;     // 0..511
    const int g  = L >> 8, c = L & 255;
    const int j  = c & 15;
    const int bh = (g << 4) | (c >> 4);
    const int b = bh >> 4, h = bh & 15;
    const int qbA = g ? (30 - 2 * j) : (2 * j);
    const int qbB = qbA + 1;

    const int t = threadIdx.x;
    const int w8 = t >> 6, l = t & 63, lid = l & 15, hi = (l >> 4) * 16;
    const int h4 = l >> 4;
    const int tile = w8 >> 2, wq = w8 & 3;
    const int qbMy = tile ? qbB : qbA;
    const int ntMy = qbMy + 1;
    const int q0My = qbMy * 64;
    const int ntB  = qbB + 1;                        // loop bound (B = A+1)

    __shared__ __align__(16) char Kt[2][8192];
    __shared__ __align__(16) char Vt[2][8192];
    __shared__ __align__(16) char Pt[2][8192];       // per-tile P

    const char* Kbh = (const char*)(Kb  + (size_t)bh * SEQ * DKD);
    const char* Vbh = (const char*)(VTb + (size_t)bh * SEQ * DKD);
    const char* Qbh = (const char*)(Qb  + (size_t)bh * SEQ * DKD);

    const f32x4 z4 = {0.f, 0.f, 0.f, 0.f};
    const int qrow = wq * 16 + lid;
    const float CLOG = 0.18033688011112042f;     // log2(e)/8
    const float NMC  = -17.312340490667560f;     // -12*log2(e)

    bf16x8 onesv;
    #pragma unroll
    for (int i = 0; i < 8; ++i) onesv[i] = (short)0x3F80;   // bf16 1.0

    bf16x8 qf[2];
    qf[0] = *(const bf16x8*)(Qbh + (size_t)(q0My + qrow) * 128 + 0  + hi);
    qf[1] = *(const bf16x8*)(Qbh + (size_t)(q0My + qrow) * 128 + 64 + hi);

    f32x4 o[4], o5;
    #pragma unroll
    for (int nf = 0; nf < 4; ++nf) o[nf] = z4;
    o5 = z4;

    // 512 threads stage K (8 KB) + V (8 KB) with one gload16 each per tile
    auto stage = [&](int buf, int kt) {
        const int k0 = kt * 64;
        int o_  = t * 16;
        int row = o_ >> 7, cl = o_ & 127;
        int sw  = (row & 7) << 4;
        char* lK = Kt[buf] + w8 * 1024;
        char* lV = Vt[buf] + w8 * 1024;
        gload16(Kbh + (size_t)(k0 + row) * 128 + (cl ^ sw), lK);
        gload16(Vbh + (size_t)row * (SEQ * 2) + k0 * 2 + (cl ^ sw), lV);
    };

    stage(0, 0);
    __syncthreads();

    for (int kt = 0; kt < ntB; ++kt) {
        const int cur = kt & 1;
        if (kt + 1 < ntB) stage(cur ^ 1, kt + 1);

        if (kt < ntMy) {
            // ---- S^T = K Q^T : lane holds S[key=nf*16+4*h4+jj][q=wq*16+lid] ----
            f32x4 sf[4];
            #pragma unroll
            for (int nf = 0; nf < 4; ++nf) {
                f32x4 a = z4;
                #pragma unroll
                for (int ks = 0; ks < 2; ++ks) {
                    int r  = nf * 16 + lid;
                    int cb = ks * 64 + hi;
                    bf16x8 kfr = *(const bf16x8*)(Kt[cur] + r * 128 + (cb ^ ((r & 7) << 4)));
                    __builtin_amdgcn_s_setprio(1);
                    a = MFMA_B16(kfr, qf[ks], a);          // swapped operands
                    __builtin_amdgcn_s_setprio(0);
                }
                sf[nf] = a;
            }

            // ---- causal mask on the diagonal tile (raw domain) ----
            if (kt == qbMy) {
                const int qloc = wq * 16 + lid;
                #pragma unroll
                for (int nf = 0; nf < 4; ++nf) {
                    #pragma unroll
                    for (int jj = 0; jj < 4; ++jj) {
                        int keyloc = nf * 16 + h4 * 4 + jj;
                        if (keyloc > qloc) sf[nf][jj] = -1e30f;
                    }
                }
            }

            // ---- fixed-shift exp: P = 2^(s*CLOG + NMC); raw v_exp_f32 ----
            uint2 pk[4];
            #pragma unroll
            for (int nf = 0; nf < 4; ++nf) {
                float p0, p1, p2, p3;
                asm("v_exp_f32 %0, %1" : "=v"(p0) : "v"(fmaf(sf[nf][0], CLOG, NMC)));
                asm("v_exp_f32 %0, %1" : "=v"(p1) : "v"(fmaf(sf[nf][1], CLOG, NMC)));
                asm("v_exp_f32 %0, %1" : "=v"(p2) : "v"(fmaf(sf[nf][2], CLOG, NMC)));
                asm("v_exp_f32 %0, %1" : "=v"(p3) : "v"(fmaf(sf[nf][3], CLOG, NMC)));
                unsigned plo, phi;
                asm("v_cvt_pk_bf16_f32 %0, %1, %2" : "=v"(plo) : "v"(p0), "v"(p1));
                asm("v_cvt_pk_bf16_f32 %0, %1, %2" : "=v"(phi) : "v"(p2), "v"(p3));
                pk[nf].x = plo; pk[nf].y = phi;
            }

            // ---- write P row-chunk (rows wave-private; no barrier needed) ----
            {
                const int rowq = wq * 16 + lid;
                const int swz  = (lid & 7) << 4;
                char* base = Pt[tile] + rowq * 128;
                #pragma unroll
                for (int nf = 0; nf < 4; ++nf)
                    *(uint2*)(base + ((nf * 32 + 8 * h4) ^ swz)) = pk[nf];
            }

            // ---- O += P V ; denom += P * ones ----
            #pragma unroll
            for (int ks = 0; ks < 2; ++ks) {
                int cb = ks * 64 + hi;
                int qr = wq * 16 + lid;
                bf16x8 pa = *(const bf16x8*)(Pt[tile] + qr * 128 + (cb ^ ((qr & 7) << 4)));
                __builtin_amdgcn_s_setprio(1);
                #pragma unroll
                for (int nf = 0; nf < 4; ++nf) {
                    int dr = nf * 16 + lid;
                    bf16x8 vb = *(const bf16x8*)(Vt[cur] + dr * 128 + (cb ^ ((dr & 7) << 4)));
                    o[nf] = MFMA_B16(pa, vb, o[nf]);
                }
                o5 = MFMA_B16(pa, onesv, o5);
                __builtin_amdgcn_s_setprio(0);
            }
        }

        __syncthreads();   // drains staged loads; protects buffer reuse
    }

    // ---- epilogue: AO bf16 [b*S+s][h*64+d]; denom is o5 (same row layout) ----
    float inv[4];
    #pragma unroll
    for (int jj = 0; jj < 4; ++jj) inv[jj] = 1.0f / o5[jj];
    #pragma unroll
    for (int nf = 0; nf < 4; ++nf)
        #pragma unroll
        for (int jj = 0; jj < 4; ++jj) {
            int srow = q0My + wq * 16 + h4 * 4 + jj;
            int col  = h * 64 + nf * 16 + lid;
            AOb[((size_t)b * SEQ + srow) * DM + col] = f2bf(o[nf][jj] * inv[jj]);
        }
}

// ---------------- launch ----------------
extern "C" void kernel_launch(void* const* d_in, const int* in_sizes, int n_in,
                              void* d_out, int out_size, void* d_ws, size_t ws_size,
                              hipStream_t stream)
{
    const float* x   = (const float*)d_in[0];
    const int*   pos = (const int*)  d_in[1];
    const float* Wq  = (const float*)d_in[2];
    const float* Wk  = (const float*)d_in[3];
    const float* Wv  = (const float*)d_in[4];
    const float* Wo  = (const float*)d_in[5];
    float* out = (float*)d_out;

    const size_t M1 = 1u << 20;                 // 1M elements
    unsigned short* ws  = (unsigned short*)d_ws;
    unsigned short* Xb    = ws;                 // 4M
    unsigned short* Wqkvb = ws + 4 * M1;        // 3M (Wq|Wk|Wv rows)
    unsigned short* Wob   = ws + 7 * M1;        // 1M
    unsigned short* Qbf   = ws + 8 * M1;        // 4M  [bh][s][64]
    unsigned short* Kbf   = ws + 12 * M1;       // 4M  [bh][s][64]
    unsigned short* VTb   = ws + 16 * M1;       // 4M  [bh][64][s]
    unsigned short* AOb   = ws + 20 * M1;       // 4M  [b*s][1024]

    convert_all<<<8192, 256, 0, stream>>>(x, Wq, Wk, Wv, Wo, Xb, Wqkvb, Wob);

    // QKV projection (epilogue scatters Q,K row-major; V transposed)
    gemm_mfma<0><<<dim3(24, 32), 256, 0, stream>>>(Xb, Wqkvb, Qbf, Kbf, VTb, nullptr);

    // RoPE in place on bf16 Q/K (standalone — fusing into the GEMM epilogue
    // spilled the accumulator to scratch: R11, 270 us + 1.6 GB writes)
    rope_bf16<<<8192, 256, 0, stream>>>(Qbf, Kbf, pos);

    // flash attention (8-wave blocks, adjacent q-tile pairs share K/V staging)
    flash_mfma<<<dim3(16, 32), 512, 0, stream>>>(Qbf, Kbf, VTb, AOb);

    // output projection
    gemm_mfma<1><<<dim3(8, 32), 256, 0, stream>>>(AOb, Wob, nullptr, nullptr, nullptr, out);
}

// Round 18
// 122.480 us; speedup vs baseline: 1.0249x; 1.0249x over previous
//
#include <hip/hip_runtime.h>
#include <math.h>

#define SEQ   2048
#define BATCH 2
#define NH    16
#define DKD   64
#define DM    1024
#define MTOT  (BATCH*SEQ)   // 4096

typedef short bf16x8 __attribute__((ext_vector_type(8)));      // 8 bf16 (4 VGPR)
typedef float f32x4  __attribute__((ext_vector_type(4)));      // MFMA C/D
typedef unsigned short u16x4 __attribute__((ext_vector_type(4)));

#define MFMA_B16(a,b,c) __builtin_amdgcn_mfma_f32_16x16x32_bf16((a),(b),(c),0,0,0)

__device__ __forceinline__ unsigned short f2bf(float f) {
    union { float f; unsigned int u; } v; v.f = f;
    unsigned int r = v.u + 0x7FFFu + ((v.u >> 16) & 1u);   // RNE
    return (unsigned short)(r >> 16);
}
__device__ __forceinline__ float bf2f(unsigned short h) {
    union { unsigned int u; float f; } v; v.u = ((unsigned int)h) << 16;
    return v.f;
}
__device__ __forceinline__ void gload16(const void* g, void* l) {
    __builtin_amdgcn_global_load_lds(
        (const __attribute__((address_space(1))) unsigned int*)g,
        (__attribute__((address_space(3))) unsigned int*)l, 16, 0, 0);
}

// ---------------- fp32 -> bf16: x + Wq + Wk + Wv + Wo in ONE launch ----------------
__global__ __launch_bounds__(256)
void convert_all(const float* __restrict__ x,  const float* __restrict__ Wq,
                 const float* __restrict__ Wk, const float* __restrict__ Wv,
                 const float* __restrict__ Wo,
                 unsigned short* __restrict__ Xb, unsigned short* __restrict__ Wqkvb,
                 unsigned short* __restrict__ Wob)
{
    int i = blockIdx.x * 256 + threadIdx.x;          // 0 .. 2M-1
    const float* src;
    unsigned short* dst;
    size_t off;
    if (i < (1 << 20)) {
        src = x; dst = Xb; off = (size_t)i;
    } else {
        int j = i - (1 << 20);
        int wsel = j >> 18;                          // 0..3
        off = (size_t)(j & ((1 << 18) - 1));
        src = (wsel == 0) ? Wq : (wsel == 1) ? Wk : (wsel == 2) ? Wv : Wo;
        dst = (wsel < 3) ? Wqkvb + (size_t)wsel * (1u << 20) : Wob;
    }
    float4 v = ((const float4*)src)[off];
    u16x4 o = { f2bf(v.x), f2bf(v.y), f2bf(v.z), f2bf(v.w) };
    *(u16x4*)&dst[off * 4] = o;
}

// ---------------- RoPE in place on bf16 Q/K  [bh][s][64] (standalone) ----------------
__global__ __launch_bounds__(256)
void rope_bf16(unsigned short* __restrict__ Qb, unsigned short* __restrict__ Kb,
               const int* __restrict__ pos)
{
    int g = blockIdx.x * 256 + threadIdx.x;      // 2M ushort4-groups (Q then K)
    int tsel = g >> 20;
    int i = g & ((1 << 20) - 1);
    unsigned short* base = tsel ? Kb : Qb;
    int d4 = i & 15;
    int s  = (i >> 4) & (SEQ - 1);
    float P = (float)pos[s];
    const float NEG_L2 = -0.41524101186092103f;  // -log2(10000)/32
    int p0 = d4 * 2, p1 = p0 + 1;
    float a0 = P * exp2f((float)p0 * NEG_L2);
    float a1 = P * exp2f((float)p1 * NEG_L2);
    float s0, c0, s1, c1;
    sincosf(a0, &s0, &c0);
    sincosf(a1, &s1, &c1);

    u16x4 v = *(u16x4*)&base[(size_t)i * 4];
    float x0 = bf2f(v[0]), x1 = bf2f(v[1]), x2 = bf2f(v[2]), x3 = bf2f(v[3]);
    u16x4 o = { f2bf(x0 * c0 - x1 * s0), f2bf(x0 * s0 + x1 * c0),
                f2bf(x2 * c1 - x3 * s1), f2bf(x2 * s1 + x3 * c1) };
    *(u16x4*)&base[(size_t)i * 4] = o;
}

// ---------------- MFMA GEMM (unchanged) ----------------
template<int MODE>
__global__ __launch_bounds__(256)
void gemm_mfma(const unsigned short* __restrict__ A, const unsigned short* __restrict__ B,
               unsigned short* __restrict__ Qb, unsigned short* __restrict__ Kb,
               unsigned short* __restrict__ VTb, float* __restrict__ Cf)
{
    const int t = threadIdx.x;
    const int w = t >> 6, l = t & 63, lid = l & 15, hi = (l >> 4) * 16;
    const int wm = w >> 1, wn = w & 1;
    const int m0 = blockIdx.y * 128, n0 = blockIdx.x * 128;

    __shared__ __align__(16) char At[2][8192];
    __shared__ __align__(16) char Bt[2][8192];

    f32x4 acc[4][4];
    const f32x4 z4 = {0.f, 0.f, 0.f, 0.f};
    #pragma unroll
    for (int i = 0; i < 4; ++i)
        #pragma unroll
        for (int j = 0; j < 4; ++j) acc[i][j] = z4;

    const char* Ab = (const char*)A;
    const char* Bb = (const char*)B;

    auto stage = [&](int buf, int kt) {
        const int kbyte = kt * 64;
        #pragma unroll
        for (int i = 0; i < 2; ++i) {
            int o   = i * 4096 + t * 16;
            int row = o >> 6, cb = o & 63;
            char* lbase_a = At[buf] + i * 4096 + (t >> 6) * 1024;
            char* lbase_b = Bt[buf] + i * 4096 + (t >> 6) * 1024;
            gload16(Ab + (size_t)(m0 + row) * 2048 + kbyte + cb, lbase_a);
            gload16(Bb + (size_t)(n0 + row) * 2048 + kbyte + cb, lbase_b);
        }
    };

    stage(0, 0);
    __syncthreads();

    const int NKT = DM / 32;
    for (int kt = 0; kt < NKT; ++kt) {
        const int cur = kt & 1;
        if (kt + 1 < NKT) stage(cur ^ 1, kt + 1);

        bf16x8 af[4], bfr[4];
        #pragma unroll
        for (int mf = 0; mf < 4; ++mf)
            af[mf] = *(const bf16x8*)(At[cur] + (wm * 64 + mf * 16 + lid) * 64 + hi);
        #pragma unroll
        for (int nf = 0; nf < 4; ++nf)
            bfr[nf] = *(const bf16x8*)(Bt[cur] + (wn * 64 + nf * 16 + lid) * 64 + hi);
        __builtin_amdgcn_s_setprio(1);
        #pragma unroll
        for (int mf = 0; mf < 4; ++mf)
            #pragma unroll
            for (int nf = 0; nf < 4; ++nf)
                acc[mf][nf] = MFMA_B16(af[mf], bfr[nf], acc[mf][nf]);
        __builtin_amdgcn_s_setprio(0);

        __syncthreads();
    }

    if (MODE == 1) {
        #pragma unroll
        for (int mf = 0; mf < 4; ++mf)
            #pragma unroll
            for (int nf = 0; nf < 4; ++nf) {
                int ncol = n0 + wn * 64 + nf * 16 + lid;
                #pragma unroll
                for (int jj = 0; jj < 4; ++jj) {
                    int mrow = m0 + wm * 64 + mf * 16 + (l >> 4) * 4 + jj;
                    Cf[(size_t)mrow * DM + ncol] = acc[mf][nf][jj];
                }
            }
    } else {
        const int z = n0 >> 10;                  // 0:Q 1:K 2:V
        const int nbase = n0 & 1023;
        #pragma unroll
        for (int mf = 0; mf < 4; ++mf)
            #pragma unroll
            for (int nf = 0; nf < 4; ++nf) {
                int ncol = nbase + wn * 64 + nf * 16 + lid;
                int h = ncol >> 6, d = ncol & 63;
                int mbase = m0 + wm * 64 + mf * 16 + (l >> 4) * 4;
                int b = mbase >> 11, s0v = mbase & 2047;
                if (z == 2) {
                    u16x4 pk = { f2bf(acc[mf][nf][0]), f2bf(acc[mf][nf][1]),
                                 f2bf(acc[mf][nf][2]), f2bf(acc[mf][nf][3]) };
                    *(u16x4*)&VTb[((size_t)(b * NH + h) * DKD + d) * SEQ + s0v] = pk;
                } else {
                    unsigned short* dst = (z == 0) ? Qb : Kb;
                    #pragma unroll
                    for (int jj = 0; jj < 4; ++jj)
                        dst[((size_t)(b * NH + h) * SEQ + (s0v + jj)) * DKD + d] =
                            f2bf(acc[mf][nf][jj]);
                }
            }
    }
}

// ---------------- MFMA flash attention: counted-vmcnt pipeline (T4) ----------------
// 512 thr: waves 0-3 = q-tile A, waves 4-7 = q-tile B = A+1 (same bh); K/V staged once.
// 3-deep K/V buffers; per round: s_waitcnt vmcnt(2) (my tile-kt loads done; tile kt+1
// stays in flight) -> s_barrier (all waves => tile kt fully resident) -> issue
// stage(kt+2) (barrier protects buf[(kt+2)%3] from last round's readers) -> compute.
// Loads get ~2 rounds to land instead of 0 (the R16 __syncthreads drained vmcnt(0)
// every round -- the known ~20%+ barrier-drain stall, m97/m218).
// Fixed-shift softmax: P = exp2(fma(s, log2e/8, -12*log2e)); denom via ones-MFMA.
__global__ __launch_bounds__(512)
void flash_mfma(const unsigned short* __restrict__ Qb, const unsigned short* __restrict__ Kb,
                const unsigned short* __restrict__ VTb, unsigned short* __restrict__ AOb)
{
    const int L  = blockIdx.y * 16 + blockIdx.x;     // 0..511
    const int g  = L >> 8, c = L & 255;
    const int j  = c & 15;
    const int bh = (g << 4) | (c >> 4);
    const int b = bh >> 4, h = bh & 15;
    const int qbA = g ? (30 - 2 * j) : (2 * j);
    const int qbB = qbA + 1;

    const int t = threadIdx.x;
    const int w8 = t >> 6, l = t & 63, lid = l & 15, hi = (l >> 4) * 16;
    const int h4 = l >> 4;
    const int tile = w8 >> 2, wq = w8 & 3;
    const int qbMy = tile ? qbB : qbA;
    const int ntMy = qbMy + 1;
    const int q0My = qbMy * 64;
    const int ntB  = qbB + 1;                        // loop bound (B = A+1), >= 2

    __shared__ __align__(16) char Kt[3][8192];
    __shared__ __align__(16) char Vt[3][8192];
    __shared__ __align__(16) char Pt[2][8192];       // per-tile P

    const char* Kbh = (const char*)(Kb  + (size_t)bh * SEQ * DKD);
    const char* Vbh = (const char*)(VTb + (size_t)bh * SEQ * DKD);
    const char* Qbh = (const char*)(Qb  + (size_t)bh * SEQ * DKD);

    const f32x4 z4 = {0.f, 0.f, 0.f, 0.f};
    const int qrow = wq * 16 + lid;
    const float CLOG = 0.18033688011112042f;     // log2(e)/8
    const float NMC  = -17.312340490667560f;     // -12*log2(e)

    bf16x8 onesv;
    #pragma unroll
    for (int i = 0; i < 8; ++i) onesv[i] = (short)0x3F80;   // bf16 1.0

    bf16x8 qf[2];
    qf[0] = *(const bf16x8*)(Qbh + (size_t)(q0My + qrow) * 128 + 0  + hi);
    qf[1] = *(const bf16x8*)(Qbh + (size_t)(q0My + qrow) * 128 + 64 + hi);

    f32x4 o[4], o5;
    #pragma unroll
    for (int nf = 0; nf < 4; ++nf) o[nf] = z4;
    o5 = z4;

    // 512 threads stage K (8 KB) + V (8 KB): exactly 2 gload16 per thread per tile
    auto stage = [&](int buf, int kt) {
        const int k0 = kt * 64;
        int o_  = t * 16;
        int row = o_ >> 7, cl = o_ & 127;
        int sw  = (row & 7) << 4;
        char* lK = Kt[buf] + w8 * 1024;
        char* lV = Vt[buf] + w8 * 1024;
        gload16(Kbh + (size_t)(k0 + row) * 128 + (cl ^ sw), lK);
        gload16(Vbh + (size_t)row * (SEQ * 2) + k0 * 2 + (cl ^ sw), lV);
    };

    // prologue: 2 tiles in flight (ntB >= 2 always)
    stage(0, 0);
    stage(1, 1);

    for (int kt = 0; kt < ntB; ++kt) {
        const int cur = kt % 3;

        // my tile-kt loads retired (tile kt+1's 2 loads may remain in flight)
        if (kt == ntB - 1) asm volatile("s_waitcnt vmcnt(0)" ::: "memory");
        else               asm volatile("s_waitcnt vmcnt(2)" ::: "memory");
        __builtin_amdgcn_s_barrier();     // all waves reached => tile kt resident;
                                          // nobody still reads buf[(kt+2)%3]
        if (kt + 2 < ntB) stage((kt + 2) % 3, kt + 2);

        if (kt < ntMy) {
            // ---- S^T = K Q^T : lane holds S[key=nf*16+4*h4+jj][q=wq*16+lid] ----
            f32x4 sf[4];
            __builtin_amdgcn_s_setprio(1);
            #pragma unroll
            for (int nf = 0; nf < 4; ++nf) {
                f32x4 a = z4;
                #pragma unroll
                for (int ks = 0; ks < 2; ++ks) {
                    int r  = nf * 16 + lid;
                    int cb = ks * 64 + hi;
                    bf16x8 kfr = *(const bf16x8*)(Kt[cur] + r * 128 + (cb ^ ((r & 7) << 4)));
                    a = MFMA_B16(kfr, qf[ks], a);          // swapped operands
                }
                sf[nf] = a;
            }
            __builtin_amdgcn_s_setprio(0);

            // ---- causal mask on the diagonal tile (raw domain) ----
            if (kt == qbMy) {
                const int qloc = wq * 16 + lid;
                #pragma unroll
                for (int nf = 0; nf < 4; ++nf) {
                    #pragma unroll
                    for (int jj = 0; jj < 4; ++jj) {
                        int keyloc = nf * 16 + h4 * 4 + jj;
                        if (keyloc > qloc) sf[nf][jj] = -1e30f;
                    }
                }
            }

            // ---- fixed-shift exp: P = 2^(s*CLOG + NMC); raw v_exp_f32 ----
            uint2 pk[4];
            #pragma unroll
            for (int nf = 0; nf < 4; ++nf) {
                float p0, p1, p2, p3;
                asm("v_exp_f32 %0, %1" : "=v"(p0) : "v"(fmaf(sf[nf][0], CLOG, NMC)));
                asm("v_exp_f32 %0, %1" : "=v"(p1) : "v"(fmaf(sf[nf][1], CLOG, NMC)));
                asm("v_exp_f32 %0, %1" : "=v"(p2) : "v"(fmaf(sf[nf][2], CLOG, NMC)));
                asm("v_exp_f32 %0, %1" : "=v"(p3) : "v"(fmaf(sf[nf][3], CLOG, NMC)));
                unsigned plo, phi;
                asm("v_cvt_pk_bf16_f32 %0, %1, %2" : "=v"(plo) : "v"(p0), "v"(p1));
                asm("v_cvt_pk_bf16_f32 %0, %1, %2" : "=v"(phi) : "v"(p2), "v"(p3));
                pk[nf].x = plo; pk[nf].y = phi;
            }

            // ---- write P row-chunk (rows wave-private; no barrier needed) ----
            {
                const int rowq = wq * 16 + lid;
                const int swz  = (lid & 7) << 4;
                char* base = Pt[tile] + rowq * 128;
                #pragma unroll
                for (int nf = 0; nf < 4; ++nf)
                    *(uint2*)(base + ((nf * 32 + 8 * h4) ^ swz)) = pk[nf];
            }

            // ---- O += P V ; denom += P * ones ----
            #pragma unroll
            for (int ks = 0; ks < 2; ++ks) {
                int cb = ks * 64 + hi;
                int qr = wq * 16 + lid;
                bf16x8 pa = *(const bf16x8*)(Pt[tile] + qr * 128 + (cb ^ ((qr & 7) << 4)));
                __builtin_amdgcn_s_setprio(1);
                #pragma unroll
                for (int nf = 0; nf < 4; ++nf) {
                    int dr = nf * 16 + lid;
                    bf16x8 vb = *(const bf16x8*)(Vt[cur] + dr * 128 + (cb ^ ((dr & 7) << 4)));
                    o[nf] = MFMA_B16(pa, vb, o[nf]);
                }
                o5 = MFMA_B16(pa, onesv, o5);
                __builtin_amdgcn_s_setprio(0);
            }
        }
    }

    // ---- epilogue: AO bf16 [b*S+s][h*64+d]; denom is o5 (same row layout) ----
    float inv[4];
    #pragma unroll
    for (int jj = 0; jj < 4; ++jj) inv[jj] = 1.0f / o5[jj];
    #pragma unroll
    for (int nf = 0; nf < 4; ++nf)
        #pragma unroll
        for (int jj = 0; jj < 4; ++jj) {
            int srow = q0My + wq * 16 + h4 * 4 + jj;
            int col  = h * 64 + nf * 16 + lid;
            AOb[((size_t)b * SEQ + srow) * DM + col] = f2bf(o[nf][jj] * inv[jj]);
        }
}

// ---------------- launch ----------------
extern "C" void kernel_launch(void* const* d_in, const int* in_sizes, int n_in,
                              void* d_out, int out_size, void* d_ws, size_t ws_size,
                              hipStream_t stream)
{
    const float* x   = (const float*)d_in[0];
    const int*   pos = (const int*)  d_in[1];
    const float* Wq  = (const float*)d_in[2];
    const float* Wk  = (const float*)d_in[3];
    const float* Wv  = (const float*)d_in[4];
    const float* Wo  = (const float*)d_in[5];
    float* out = (float*)d_out;

    const size_t M1 = 1u << 20;                 // 1M elements
    unsigned short* ws  = (unsigned short*)d_ws;
    unsigned short* Xb    = ws;                 // 4M
    unsigned short* Wqkvb = ws + 4 * M1;        // 3M (Wq|Wk|Wv rows)
    unsigned short* Wob   = ws + 7 * M1;        // 1M
    unsigned short* Qbf   = ws + 8 * M1;        // 4M  [bh][s][64]
    unsigned short* Kbf   = ws + 12 * M1;       // 4M  [bh][s][64]
    unsigned short* VTb   = ws + 16 * M1;       // 4M  [bh][64][s]
    unsigned short* AOb   = ws + 20 * M1;       // 4M  [b*s][1024]

    convert_all<<<8192, 256, 0, stream>>>(x, Wq, Wk, Wv, Wo, Xb, Wqkvb, Wob);

    // QKV projection (epilogue scatters Q,K row-major; V transposed)
    gemm_mfma<0><<<dim3(24, 32), 256, 0, stream>>>(Xb, Wqkvb, Qbf, Kbf, VTb, nullptr);

    // RoPE in place on bf16 Q/K (standalone — fusing into the GEMM epilogue
    // spilled the accumulator to scratch: R11, 270 us + 1.6 GB writes)
    rope_bf16<<<8192, 256, 0, stream>>>(Qbf, Kbf, pos);

    // flash attention (8-wave blocks, counted-vmcnt 3-deep pipeline)
    flash_mfma<<<dim3(16, 32), 512, 0, stream>>>(Qbf, Kbf, VTb, AOb);

    // output projection
    gemm_mfma<1><<<dim3(8, 32), 256, 0, stream>>>(AOb, Wob, nullptr, nullptr, nullptr, out);
}

// Round 19
// 119.401 us; speedup vs baseline: 1.0514x; 1.0258x over previous
//
#include <hip/hip_runtime.h>
#include <math.h>

#define SEQ   2048
#define BATCH 2
#define NH    16
#define DKD   64
#define DM    1024
#define MTOT  (BATCH*SEQ)   // 4096

typedef short bf16x8 __attribute__((ext_vector_type(8)));      // 8 bf16 (4 VGPR)
typedef float f32x4  __attribute__((ext_vector_type(4)));      // MFMA C/D
typedef unsigned short u16x4 __attribute__((ext_vector_type(4)));
typedef unsigned short u16x8 __attribute__((ext_vector_type(8)));

#define MFMA_B16(a,b,c) __builtin_amdgcn_mfma_f32_16x16x32_bf16((a),(b),(c),0,0,0)

__device__ __forceinline__ unsigned short f2bf(float f) {
    union { float f; unsigned int u; } v; v.f = f;
    unsigned int r = v.u + 0x7FFFu + ((v.u >> 16) & 1u);   // RNE
    return (unsigned short)(r >> 16);
}
__device__ __forceinline__ float bf2f(unsigned short h) {
    union { unsigned int u; float f; } v; v.u = ((unsigned int)h) << 16;
    return v.f;
}
__device__ __forceinline__ void gload16(const void* g, void* l) {
    __builtin_amdgcn_global_load_lds(
        (const __attribute__((address_space(1))) unsigned int*)g,
        (__attribute__((address_space(3))) unsigned int*)l, 16, 0, 0);
}

// ---------------- fp32 -> bf16: x + Wq + Wk + Wv + Wo, 32 B/thread ----------------
__global__ __launch_bounds__(256)
void convert_all(const float* __restrict__ x,  const float* __restrict__ Wq,
                 const float* __restrict__ Wk, const float* __restrict__ Wv,
                 const float* __restrict__ Wo,
                 unsigned short* __restrict__ Xb, unsigned short* __restrict__ Wqkvb,
                 unsigned short* __restrict__ Wob)
{
    int i = blockIdx.x * 256 + threadIdx.x;          // 0 .. 1M-1, each 8 floats
    const float* src;
    unsigned short* dst;
    size_t off;
    if (i < (1 << 19)) {                             // x: 4M floats = 512K groups
        src = x; dst = Xb; off = (size_t)i;
    } else {
        int j = i - (1 << 19);
        int wsel = j >> 17;                          // 0..3 (1M floats = 128K groups each)
        off = (size_t)(j & ((1 << 17) - 1));
        src = (wsel == 0) ? Wq : (wsel == 1) ? Wk : (wsel == 2) ? Wv : Wo;
        dst = (wsel < 3) ? Wqkvb + (size_t)wsel * (1u << 20) : Wob;
    }
    float4 v0 = ((const float4*)src)[off * 2];
    float4 v1 = ((const float4*)src)[off * 2 + 1];
    u16x8 o = { f2bf(v0.x), f2bf(v0.y), f2bf(v0.z), f2bf(v0.w),
                f2bf(v1.x), f2bf(v1.y), f2bf(v1.z), f2bf(v1.w) };
    *(u16x8*)&dst[off * 8] = o;
}

// ---------------- RoPE in place on bf16 Q/K  [bh][s][64], 16 B/thread ----------------
__global__ __launch_bounds__(256)
void rope_bf16(unsigned short* __restrict__ Qb, unsigned short* __restrict__ Kb,
               const int* __restrict__ pos)
{
    int idx = blockIdx.x * 256 + threadIdx.x;    // 0..1M-1 (Q then K), each 8 bf16
    int tsel = idx >> 19;
    int i = idx & ((1 << 19) - 1);
    unsigned short* base = tsel ? Kb : Qb;
    int d8 = i & 7;                              // 8-elem chunk within row of 64
    int s  = (i >> 3) & (SEQ - 1);
    float P = (float)pos[s];
    const float NEG_L2 = -0.41524101186092103f;  // -log2(10000)/32

    u16x8 v = *(u16x8*)&base[(size_t)i * 8];
    u16x8 o;
    #pragma unroll
    for (int k = 0; k < 4; ++k) {
        int pi = d8 * 4 + k;                     // pair index 0..31
        float ang = P * exp2f((float)pi * NEG_L2);
        float sn, cs;
        sincosf(ang, &sn, &cs);
        float e0 = bf2f(v[2*k]), e1 = bf2f(v[2*k + 1]);
        o[2*k]     = f2bf(e0 * cs - e1 * sn);
        o[2*k + 1] = f2bf(e0 * sn + e1 * cs);
    }
    *(u16x8*)&base[(size_t)i * 8] = o;
}

// ---------------- MFMA GEMM: 3-deep counted-vmcnt pipeline + T2 read-swizzle -------
// C[M][N] = A[M][K] x B[N][K]^T, bf16 in / f32 acc; 128x128 tile, BK=32, 4 waves.
// LDS rows are 64 B; unswizzled frag reads are phase-wise ~8-way bank conflicted
// (bank = {row[0], col[5:2]}). Swizzle byte ^= ((row>>1)&3)<<4 -> bank =
// {row[0], row[2:1]^chunk}, bijective over row mod 8 => 2-way (free, m136).
// Rule #21: linear LDS dest (gload16), inverse-swizzled GLOBAL source, same XOR on
// reads. Counted vmcnt(4) + raw s_barrier (R18-proven in flash): loads get 2 rounds
// to land; no per-round vmcnt(0) drain.
// MODE 0: N=3072, epilogue scatters Q,K ([bh][s][d]) and V transposed ([bh][d][s])
// MODE 1: N=1024, epilogue writes fp32 row-major C
template<int MODE>
__global__ __launch_bounds__(256)
void gemm_mfma(const unsigned short* __restrict__ A, const unsigned short* __restrict__ B,
               unsigned short* __restrict__ Qb, unsigned short* __restrict__ Kb,
               unsigned short* __restrict__ VTb, float* __restrict__ Cf)
{
    const int t = threadIdx.x;
    const int w = t >> 6, l = t & 63, lid = l & 15, hi = (l >> 4) * 16;
    const int wm = w >> 1, wn = w & 1;
    const int m0 = blockIdx.y * 128, n0 = blockIdx.x * 128;

    __shared__ __align__(16) char At[3][8192];   // [128 m][32 k] bf16, 64 B rows
    __shared__ __align__(16) char Bt[3][8192];

    f32x4 acc[4][4];
    const f32x4 z4 = {0.f, 0.f, 0.f, 0.f};
    #pragma unroll
    for (int i = 0; i < 4; ++i)
        #pragma unroll
        for (int j = 0; j < 4; ++j) acc[i][j] = z4;

    const char* Ab = (const char*)A;
    const char* Bb = (const char*)B;

    auto stage = [&](int buf, int kt) {          // 4 gload16 per thread
        const int kbyte = kt * 64;
        #pragma unroll
        for (int i = 0; i < 2; ++i) {
            int o   = i * 4096 + t * 16;
            int row = o >> 6, cb = o & 63;
            int sw  = ((row >> 1) & 3) << 4;     // T2: pre-swizzle global source
            char* lbase_a = At[buf] + i * 4096 + (t >> 6) * 1024;
            char* lbase_b = Bt[buf] + i * 4096 + (t >> 6) * 1024;
            gload16(Ab + (size_t)(m0 + row) * 2048 + kbyte + (cb ^ sw), lbase_a);
            gload16(Bb + (size_t)(n0 + row) * 2048 + kbyte + (cb ^ sw), lbase_b);
        }
    };

    const int NKT = DM / 32;                     // 32
    stage(0, 0);
    stage(1, 1);

    for (int kt = 0; kt < NKT; ++kt) {
        const int cur = kt % 3;
        if (kt == NKT - 1) asm volatile("s_waitcnt vmcnt(0)" ::: "memory");
        else               asm volatile("s_waitcnt vmcnt(4)" ::: "memory");
        __builtin_amdgcn_s_barrier();            // tile kt resident block-wide;
                                                 // buf[(kt+2)%3] free of readers
        if (kt + 2 < NKT) stage((kt + 2) % 3, kt + 2);

        bf16x8 af[4], bfr[4];
        #pragma unroll
        for (int mf = 0; mf < 4; ++mf) {
            int ar = wm * 64 + mf * 16 + lid;
            af[mf] = *(const bf16x8*)(At[cur] + ar * 64 + (hi ^ (((ar >> 1) & 3) << 4)));
        }
        #pragma unroll
        for (int nf = 0; nf < 4; ++nf) {
            int br = wn * 64 + nf * 16 + lid;
            bfr[nf] = *(const bf16x8*)(Bt[cur] + br * 64 + (hi ^ (((br >> 1) & 3) << 4)));
        }
        __builtin_amdgcn_s_setprio(1);
        #pragma unroll
        for (int mf = 0; mf < 4; ++mf)
            #pragma unroll
            for (int nf = 0; nf < 4; ++nf)
                acc[mf][nf] = MFMA_B16(af[mf], bfr[nf], acc[mf][nf]);
        __builtin_amdgcn_s_setprio(0);
    }

    if (MODE == 1) {
        #pragma unroll
        for (int mf = 0; mf < 4; ++mf)
            #pragma unroll
            for (int nf = 0; nf < 4; ++nf) {
                int ncol = n0 + wn * 64 + nf * 16 + lid;
                #pragma unroll
                for (int jj = 0; jj < 4; ++jj) {
                    int mrow = m0 + wm * 64 + mf * 16 + (l >> 4) * 4 + jj;
                    Cf[(size_t)mrow * DM + ncol] = acc[mf][nf][jj];
                }
            }
    } else {
        const int z = n0 >> 10;                  // 0:Q 1:K 2:V
        const int nbase = n0 & 1023;
        #pragma unroll
        for (int mf = 0; mf < 4; ++mf)
            #pragma unroll
            for (int nf = 0; nf < 4; ++nf) {
                int ncol = nbase + wn * 64 + nf * 16 + lid;
                int h = ncol >> 6, d = ncol & 63;
                int mbase = m0 + wm * 64 + mf * 16 + (l >> 4) * 4;
                int b = mbase >> 11, s0v = mbase & 2047;
                if (z == 2) {
                    u16x4 pk = { f2bf(acc[mf][nf][0]), f2bf(acc[mf][nf][1]),
                                 f2bf(acc[mf][nf][2]), f2bf(acc[mf][nf][3]) };
                    *(u16x4*)&VTb[((size_t)(b * NH + h) * DKD + d) * SEQ + s0v] = pk;
                } else {
                    unsigned short* dst = (z == 0) ? Qb : Kb;
                    #pragma unroll
                    for (int jj = 0; jj < 4; ++jj)
                        dst[((size_t)(b * NH + h) * SEQ + (s0v + jj)) * DKD + d] =
                            f2bf(acc[mf][nf][jj]);
                }
            }
    }
}

// ---------------- MFMA flash attention: counted-vmcnt pipeline (unchanged R18) -------
__global__ __launch_bounds__(512)
void flash_mfma(const unsigned short* __restrict__ Qb, const unsigned short* __restrict__ Kb,
                const unsigned short* __restrict__ VTb, unsigned short* __restrict__ AOb)
{
    const int L  = blockIdx.y * 16 + blockIdx.x;     // 0..511
    const int g  = L >> 8, c = L & 255;
    const int j  = c & 15;
    const int bh = (g << 4) | (c >> 4);
    const int b = bh >> 4, h = bh & 15;
    const int qbA = g ? (30 - 2 * j) : (2 * j);
    const int qbB = qbA + 1;

    const int t = threadIdx.x;
    const int w8 = t >> 6, l = t & 63, lid = l & 15, hi = (l >> 4) * 16;
    const int h4 = l >> 4;
    const int tile = w8 >> 2, wq = w8 & 3;
    const int qbMy = tile ? qbB : qbA;
    const int ntMy = qbMy + 1;
    const int q0My = qbMy * 64;
    const int ntB  = qbB + 1;                        // loop bound (B = A+1), >= 2

    __shared__ __align__(16) char Kt[3][8192];
    __shared__ __align__(16) char Vt[3][8192];
    __shared__ __align__(16) char Pt[2][8192];       // per-tile P

    const char* Kbh = (const char*)(Kb  + (size_t)bh * SEQ * DKD);
    const char* Vbh = (const char*)(VTb + (size_t)bh * SEQ * DKD);
    const char* Qbh = (const char*)(Qb  + (size_t)bh * SEQ * DKD);

    const f32x4 z4 = {0.f, 0.f, 0.f, 0.f};
    const int qrow = wq * 16 + lid;
    const float CLOG = 0.18033688011112042f;     // log2(e)/8
    const float NMC  = -17.312340490667560f;     // -12*log2(e)

    bf16x8 onesv;
    #pragma unroll
    for (int i = 0; i < 8; ++i) onesv[i] = (short)0x3F80;   // bf16 1.0

    bf16x8 qf[2];
    qf[0] = *(const bf16x8*)(Qbh + (size_t)(q0My + qrow) * 128 + 0  + hi);
    qf[1] = *(const bf16x8*)(Qbh + (size_t)(q0My + qrow) * 128 + 64 + hi);

    f32x4 o[4], o5;
    #pragma unroll
    for (int nf = 0; nf < 4; ++nf) o[nf] = z4;
    o5 = z4;

    auto stage = [&](int buf, int kt) {
        const int k0 = kt * 64;
        int o_  = t * 16;
        int row = o_ >> 7, cl = o_ & 127;
        int sw  = (row & 7) << 4;
        char* lK = Kt[buf] + w8 * 1024;
        char* lV = Vt[buf] + w8 * 1024;
        gload16(Kbh + (size_t)(k0 + row) * 128 + (cl ^ sw), lK);
        gload16(Vbh + (size_t)row * (SEQ * 2) + k0 * 2 + (cl ^ sw), lV);
    };

    stage(0, 0);
    stage(1, 1);

    for (int kt = 0; kt < ntB; ++kt) {
        const int cur = kt % 3;

        if (kt == ntB - 1) asm volatile("s_waitcnt vmcnt(0)" ::: "memory");
        else               asm volatile("s_waitcnt vmcnt(2)" ::: "memory");
        __builtin_amdgcn_s_barrier();
        if (kt + 2 < ntB) stage((kt + 2) % 3, kt + 2);

        if (kt < ntMy) {
            // ---- S^T = K Q^T ----
            f32x4 sf[4];
            __builtin_amdgcn_s_setprio(1);
            #pragma unroll
            for (int nf = 0; nf < 4; ++nf) {
                f32x4 a = z4;
                #pragma unroll
                for (int ks = 0; ks < 2; ++ks) {
                    int r  = nf * 16 + lid;
                    int cb = ks * 64 + hi;
                    bf16x8 kfr = *(const bf16x8*)(Kt[cur] + r * 128 + (cb ^ ((r & 7) << 4)));
                    a = MFMA_B16(kfr, qf[ks], a);          // swapped operands
                }
                sf[nf] = a;
            }
            __builtin_amdgcn_s_setprio(0);

            // ---- causal mask on the diagonal tile ----
            if (kt == qbMy) {
                const int qloc = wq * 16 + lid;
                #pragma unroll
                for (int nf = 0; nf < 4; ++nf) {
                    #pragma unroll
                    for (int jj = 0; jj < 4; ++jj) {
                        int keyloc = nf * 16 + h4 * 4 + jj;
                        if (keyloc > qloc) sf[nf][jj] = -1e30f;
                    }
                }
            }

            // ---- fixed-shift exp ----
            uint2 pk[4];
            #pragma unroll
            for (int nf = 0; nf < 4; ++nf) {
                float p0, p1, p2, p3;
                asm("v_exp_f32 %0, %1" : "=v"(p0) : "v"(fmaf(sf[nf][0], CLOG, NMC)));
                asm("v_exp_f32 %0, %1" : "=v"(p1) : "v"(fmaf(sf[nf][1], CLOG, NMC)));
                asm("v_exp_f32 %0, %1" : "=v"(p2) : "v"(fmaf(sf[nf][2], CLOG, NMC)));
                asm("v_exp_f32 %0, %1" : "=v"(p3) : "v"(fmaf(sf[nf][3], CLOG, NMC)));
                unsigned plo, phi;
                asm("v_cvt_pk_bf16_f32 %0, %1, %2" : "=v"(plo) : "v"(p0), "v"(p1));
                asm("v_cvt_pk_bf16_f32 %0, %1, %2" : "=v"(phi) : "v"(p2), "v"(p3));
                pk[nf].x = plo; pk[nf].y = phi;
            }

            // ---- write P row-chunk ----
            {
                const int rowq = wq * 16 + lid;
                const int swz  = (lid & 7) << 4;
                char* base = Pt[tile] + rowq * 128;
                #pragma unroll
                for (int nf = 0; nf < 4; ++nf)
                    *(uint2*)(base + ((nf * 32 + 8 * h4) ^ swz)) = pk[nf];
            }

            // ---- O += P V ; denom += P * ones ----
            #pragma unroll
            for (int ks = 0; ks < 2; ++ks) {
                int cb = ks * 64 + hi;
                int qr = wq * 16 + lid;
                bf16x8 pa = *(const bf16x8*)(Pt[tile] + qr * 128 + (cb ^ ((qr & 7) << 4)));
                __builtin_amdgcn_s_setprio(1);
                #pragma unroll
                for (int nf = 0; nf < 4; ++nf) {
                    int dr = nf * 16 + lid;
                    bf16x8 vb = *(const bf16x8*)(Vt[cur] + dr * 128 + (cb ^ ((dr & 7) << 4)));
                    o[nf] = MFMA_B16(pa, vb, o[nf]);
                }
                o5 = MFMA_B16(pa, onesv, o5);
                __builtin_amdgcn_s_setprio(0);
            }
        }
    }

    // ---- epilogue ----
    float inv[4];
    #pragma unroll
    for (int jj = 0; jj < 4; ++jj) inv[jj] = 1.0f / o5[jj];
    #pragma unroll
    for (int nf = 0; nf < 4; ++nf)
        #pragma unroll
        for (int jj = 0; jj < 4; ++jj) {
            int srow = q0My + wq * 16 + h4 * 4 + jj;
            int col  = h * 64 + nf * 16 + lid;
            AOb[((size_t)b * SEQ + srow) * DM + col] = f2bf(o[nf][jj] * inv[jj]);
        }
}

// ---------------- launch ----------------
extern "C" void kernel_launch(void* const* d_in, const int* in_sizes, int n_in,
                              void* d_out, int out_size, void* d_ws, size_t ws_size,
                              hipStream_t stream)
{
    const float* x   = (const float*)d_in[0];
    const int*   pos = (const int*)  d_in[1];
    const float* Wq  = (const float*)d_in[2];
    const float* Wk  = (const float*)d_in[3];
    const float* Wv  = (const float*)d_in[4];
    const float* Wo  = (const float*)d_in[5];
    float* out = (float*)d_out;

    const size_t M1 = 1u << 20;                 // 1M elements
    unsigned short* ws  = (unsigned short*)d_ws;
    unsigned short* Xb    = ws;                 // 4M
    unsigned short* Wqkvb = ws + 4 * M1;        // 3M (Wq|Wk|Wv rows)
    unsigned short* Wob   = ws + 7 * M1;        // 1M
    unsigned short* Qbf   = ws + 8 * M1;        // 4M  [bh][s][64]
    unsigned short* Kbf   = ws + 12 * M1;       // 4M  [bh][s][64]
    unsigned short* VTb   = ws + 16 * M1;       // 4M  [bh][64][s]
    unsigned short* AOb   = ws + 20 * M1;       // 4M  [b*s][1024]

    convert_all<<<4096, 256, 0, stream>>>(x, Wq, Wk, Wv, Wo, Xb, Wqkvb, Wob);

    // QKV projection (epilogue scatters Q,K row-major; V transposed)
    gemm_mfma<0><<<dim3(24, 32), 256, 0, stream>>>(Xb, Wqkvb, Qbf, Kbf, VTb, nullptr);

    // RoPE in place on bf16 Q/K (standalone — fusing into the GEMM epilogue
    // spilled the accumulator to scratch: R11, 270 us + 1.6 GB writes)
    rope_bf16<<<4096, 256, 0, stream>>>(Qbf, Kbf, pos);

    // flash attention (8-wave blocks, counted-vmcnt 3-deep pipeline)
    flash_mfma<<<dim3(16, 32), 512, 0, stream>>>(Qbf, Kbf, VTb, AOb);

    // output projection
    gemm_mfma<1><<<dim3(8, 32), 256, 0, stream>>>(AOb, Wob, nullptr, nullptr, nullptr, out);
}